// Round 1
// baseline (175.123 us; speedup 1.0000x reference)
//
#include <hip/hip_runtime.h>
#include <math.h>

#define EPSF 1e-7f

// Exact replication of the reference _np_J entry (float64 math):
// J^l = diag((-1)^i) @ d^l(pi/2). At beta=pi/2, c=s=1/sqrt(2), so
// c^(2l+mp-m-2k) * s^(m-mp+2k) == 2^{-l} for every k.
__device__ __forceinline__ float j_entry(int ell, int mi, int mpi) {
    if (ell == 0) return 1.0f;
    const double fact[8] = {1.0, 1.0, 2.0, 6.0, 24.0, 120.0, 720.0, 5040.0};
    int m  = ell - mi;
    int mp = ell - mpi;
    double pref  = sqrt(fact[ell + m] * fact[ell - m] * fact[ell + mp] * fact[ell - mp]);
    double scale = 1.0 / (double)(1 << ell);
    int k0 = max(0, m - mp);
    int k1 = min(ell + m, ell - mp);
    double val = 0.0;
    for (int k = k0; k <= k1; ++k) {
        double denom = fact[ell + m - k] * fact[ell - mp - k] * fact[k + mp - m] * fact[k];
        double t = pref / denom * scale;
        val += ((m - mp + k) & 1) ? -t : t;
    }
    return (float)((mi & 1) ? -val : val);
}

// Row 0 (l=0 block): D^0 == 1 always.
__device__ void run_l0(float* __restrict__ out, int E, int g0, int stride) {
    for (int e = g0; e < E; e += stride) {
        float4* op = reinterpret_cast<float4*>(out + (size_t)e * 256);
        op[0] = make_float4(1.f, 0.f, 0.f, 0.f);
        op[1] = make_float4(0.f, 0.f, 0.f, 0.f);
        op[2] = make_float4(0.f, 0.f, 0.f, 0.f);
        op[3] = make_float4(0.f, 0.f, 0.f, 0.f);
    }
}

// Lane owns row (L*L + li) of the 16x16 output for a stream of edges.
// D^L[li, :] = row(li) of Za * (J Zb J):
//   u_k = ca*J[li,k] + sa*J[2L-li,k]          (ca=cos(m_i a), sa=sin(m_i a))
//   w_k = u_k*cos(m_k b) - u_{2L-k}*sin(m_k b)
//   d_v = sum_k w_k * J[k,v]
template<int L>
__device__ void run_rows(const float* __restrict__ JL, int li,
                         const float* __restrict__ ev, float* __restrict__ out,
                         int E, int g0, int stride) {
    constexpr int DIM = 2 * L + 1;
    constexpr int OFF = L * L;

    float Jb[DIM][DIM];
#pragma unroll
    for (int k = 0; k < DIM; ++k)
#pragma unroll
        for (int v = 0; v < DIM; ++v)
            Jb[k][v] = JL[k * DIM + v];

    float Jmu[DIM], Jrev[DIM];
#pragma unroll
    for (int k = 0; k < DIM; ++k) {
        Jmu[k]  = JL[li * DIM + k];            // runtime li: LDS read is fine
        Jrev[k] = JL[(2 * L - li) * DIM + k];
    }
    const int m_i = L - li;
    const int am  = (m_i < 0) ? -m_i : m_i;

    for (int e = g0; e < E; e += stride) {
        float x = ev[3 * e + 0];
        float y = ev[3 * e + 1];
        float z = ev[3 * e + 2];

        float r2xy = x * x + y * y;
        float r    = sqrtf(r2xy + z * z);
        float cb   = z / fmaxf(r, EPSF);
        cb = fminf(fmaxf(cb, -1.0f + EPSF), 1.0f - EPSF);
        float sb = sqrtf(fmaxf(1.0f - cb * cb, 0.0f));   // beta in [0,pi] -> sin >= 0

        bool  degen   = (fabsf(x) < EPSF) && (fabsf(y) < EPSF);
        float rho     = sqrtf(r2xy);
        float inv_rho = 1.0f / fmaxf(rho, EPSF);
        float ca1 = degen ? 1.0f : x * inv_rho;          // cos(atan2(y,x))
        float sa1 = degen ? 0.0f : y * inv_rho;          // sin(atan2(y,x))

        // Chebyshev multi-angle (all indices compile-time after unroll)
        float CA[4], SA[4], CB[4], SB[4];
        CA[0] = 1.f; SA[0] = 0.f; CB[0] = 1.f; SB[0] = 0.f;
        CA[1] = ca1; SA[1] = sa1; CB[1] = cb;  SB[1] = sb;
#pragma unroll
        for (int q = 2; q <= L; ++q) {
            CA[q] = CA[q - 1] * ca1 - SA[q - 1] * sa1;
            SA[q] = SA[q - 1] * ca1 + CA[q - 1] * sa1;
            CB[q] = CB[q - 1] * cb  - SB[q - 1] * sb;
            SB[q] = SB[q - 1] * cb  + CB[q - 1] * sb;
        }

        float ca = CA[0], sa = SA[0];
        if (L >= 1 && am == 1) { ca = CA[1]; sa = SA[1]; }
        if (L >= 2 && am == 2) { ca = CA[2]; sa = SA[2]; }
        if (L >= 3 && am == 3) { ca = CA[3]; sa = SA[3]; }
        if (m_i < 0) sa = -sa;

        float u[DIM], w[DIM];
#pragma unroll
        for (int k = 0; k < DIM; ++k)
            u[k] = ca * Jmu[k] + sa * Jrev[k];
#pragma unroll
        for (int k = 0; k < DIM; ++k) {
            const int mk  = L - k;
            const int amk = (mk < 0) ? -mk : mk;
            float cbk = CB[amk];
            float sbk = (mk < 0) ? -SB[amk] : SB[amk];
            w[k] = u[k] * cbk - u[2 * L - k] * sbk;
        }

        float o[16];
#pragma unroll
        for (int c = 0; c < 16; ++c) o[c] = 0.0f;
#pragma unroll
        for (int v = 0; v < DIM; ++v) {
            float acc = 0.0f;
#pragma unroll
            for (int k = 0; k < DIM; ++k) acc += w[k] * Jb[k][v];
            o[OFF + v] = acc;                 // OFF constexpr -> static indexing
        }

        float4* op = reinterpret_cast<float4*>(out + (size_t)e * 256 + (size_t)(OFF + li) * 16);
        op[0] = make_float4(o[0],  o[1],  o[2],  o[3]);
        op[1] = make_float4(o[4],  o[5],  o[6],  o[7]);
        op[2] = make_float4(o[8],  o[9],  o[10], o[11]);
        op[3] = make_float4(o[12], o[13], o[14], o[15]);
    }
}

__global__ __launch_bounds__(256)
void EdgeRotation_49435073577214_kernel(const float* __restrict__ ev,
                                        float* __restrict__ out, int E) {
    // J matrices (constant) computed once per block into LDS, packed:
    // l=0 at [0], l=1 at [1..9], l=2 at [10..34], l=3 at [35..83]
    __shared__ float Jlds[84];
    int tid = threadIdx.x;
    if (tid < 84) {
        int l, rem;
        if      (tid == 0) { l = 0; rem = 0; }
        else if (tid < 10) { l = 1; rem = tid - 1; }
        else if (tid < 35) { l = 2; rem = tid - 10; }
        else               { l = 3; rem = tid - 35; }
        int dim = 2 * l + 1;
        Jlds[tid] = j_entry(l, rem / dim, rem % dim);
    }
    __syncthreads();

    int i      = tid & 15;                                    // output row
    int gg     = (int)((blockIdx.x * blockDim.x + tid) >> 4); // edge group id
    int stride = (int)((gridDim.x * blockDim.x) >> 4);

    if      (i == 0) run_l0(out, E, gg, stride);
    else if (i < 4)  run_rows<1>(Jlds + 1,  i - 1, ev, out, E, gg, stride);
    else if (i < 9)  run_rows<2>(Jlds + 10, i - 4, ev, out, E, gg, stride);
    else             run_rows<3>(Jlds + 35, i - 9, ev, out, E, gg, stride);
}

extern "C" void kernel_launch(void* const* d_in, const int* in_sizes, int n_in,
                              void* d_out, int out_size, void* d_ws, size_t ws_size,
                              hipStream_t stream) {
    const float* ev  = (const float*)d_in[0];
    float*       out = (float*)d_out;
    int E = in_sizes[0] / 3;   // [E,3] flat

    dim3 grid(2048), block(256);
    hipLaunchKernelGGL(EdgeRotation_49435073577214_kernel, grid, block, 0, stream,
                       ev, out, E);
}